// Round 6
// baseline (212.677 us; speedup 1.0000x reference)
//
#include <hip/hip_runtime.h>

#define EPS 1e-7f
#define BLOCK 256
#define ITERS 4
#define TCOL_MASK 16383   // T-1, T = 16384 (bench shape)

__device__ __forceinline__ float term_of(float z, float w, float lp) {
    const float r = __logf(1.f / (1.f + __expf(-z)) + EPS);
    return w * w * r * lp;
}

// Intra-block reduce + last-block-finishes finalize (pattern validated in R2).
__device__ __forceinline__ void block_reduce_and_finish(
    double num, double den, float* __restrict__ out,
    unsigned long long* __restrict__ slots, unsigned int* __restrict__ count)
{
#pragma unroll
    for (int off = 32; off > 0; off >>= 1) {
        num += __shfl_down(num, off, 64);
        den += __shfl_down(den, off, 64);
    }
    __shared__ double s_n[BLOCK / 64], s_d[BLOCK / 64];
    __shared__ int lastFlag;
    const int lane = threadIdx.x & 63;
    const int wid  = threadIdx.x >> 6;
    if (lane == 0) { s_n[wid] = num; s_d[wid] = den; }
    __syncthreads();
    if (threadIdx.x == 0) {
        const double n = (s_n[0] + s_n[1]) + (s_n[2] + s_n[3]);
        const double d = (s_d[0] + s_d[1]) + (s_d[2] + s_d[3]);
        // device-scope publish (safe across non-coherent XCD L2s)
        atomicExch(&slots[2 * blockIdx.x],     (unsigned long long)__double_as_longlong(n));
        atomicExch(&slots[2 * blockIdx.x + 1], (unsigned long long)__double_as_longlong(d));
        __threadfence();
        const unsigned int old = atomicAdd(count, 1u);
        lastFlag = (old == (unsigned int)(gridDim.x - 1)) ? 1 : 0;
    }
    __syncthreads();

    if (lastFlag) {
        __threadfence();
        double n = 0.0, d = 0.0;
        for (int j = threadIdx.x; j < (int)gridDim.x; j += BLOCK) {
            n += __longlong_as_double((long long)atomicAdd(&slots[2 * j],     0ULL));
            d += __longlong_as_double((long long)atomicAdd(&slots[2 * j + 1], 0ULL));
        }
#pragma unroll
        for (int off = 32; off > 0; off >>= 1) {
            n += __shfl_down(n, off, 64);
            d += __shfl_down(d, off, 64);
        }
        if (lane == 0) { s_n[wid] = n; s_d[wid] = d; }
        __syncthreads();
        if (threadIdx.x == 0) {
            out[0] = (float)(((s_n[0] + s_n[1]) + (s_n[2] + s_n[3])) /
                             ((s_d[0] + s_d[1]) + (s_d[2] + s_d[3])));
        }
    }
}

// Fast path: requires n4 % (BLOCK*ITERS) == 0. All 12 dwordx4 loads issued
// straight-line (R5 structure — at its ~16 µs HBM floor per R3–R5 A/B).
__global__ __launch_bounds__(BLOCK, 4) void reinforce_fast(
    const float* __restrict__ log_probs,
    const float* __restrict__ logits,
    const float* __restrict__ weight,
    float* __restrict__ out,
    unsigned long long* __restrict__ slots,
    unsigned int* __restrict__ count)
{
    const float4* __restrict__ lpv = (const float4*)log_probs;
    const float4* __restrict__ zv  = (const float4*)logits;
    const float4* __restrict__ wv  = (const float4*)weight;

    const long long base = (long long)blockIdx.x * (BLOCK * ITERS) + threadIdx.x;

    const float4 z0  = zv[base];
    const float4 w0  = wv[base];
    const float4 lp0 = lpv[base];
    const float4 z1  = zv[base + BLOCK];
    const float4 w1  = wv[base + BLOCK];
    const float4 lp1 = lpv[base + BLOCK];
    const float4 z2  = zv[base + 2 * BLOCK];
    const float4 w2  = wv[base + 2 * BLOCK];
    const float4 lp2 = lpv[base + 2 * BLOCK];
    const float4 z3  = zv[base + 3 * BLOCK];
    const float4 w3  = wv[base + 3 * BLOCK];
    const float4 lp3 = lpv[base + 3 * BLOCK];

    double num = 0.0, den = 0.0;
    {
        const int s = (int)((base << 2) & TCOL_MASK);
        const float fn = term_of(z0.x, w0.x, lp0.x) * (float)(s + 1)
                       + term_of(z0.y, w0.y, lp0.y) * (float)(s + 2)
                       + term_of(z0.z, w0.z, lp0.z) * (float)(s + 3)
                       + term_of(z0.w, w0.w, lp0.w) * (float)(s + 4);
        num += (double)fn;
        den += (double)((w0.x + w0.y) + (w0.z + w0.w));
    }
    {
        const int s = (int)(((base + BLOCK) << 2) & TCOL_MASK);
        const float fn = term_of(z1.x, w1.x, lp1.x) * (float)(s + 1)
                       + term_of(z1.y, w1.y, lp1.y) * (float)(s + 2)
                       + term_of(z1.z, w1.z, lp1.z) * (float)(s + 3)
                       + term_of(z1.w, w1.w, lp1.w) * (float)(s + 4);
        num += (double)fn;
        den += (double)((w1.x + w1.y) + (w1.z + w1.w));
    }
    {
        const int s = (int)(((base + 2 * BLOCK) << 2) & TCOL_MASK);
        const float fn = term_of(z2.x, w2.x, lp2.x) * (float)(s + 1)
                       + term_of(z2.y, w2.y, lp2.y) * (float)(s + 2)
                       + term_of(z2.z, w2.z, lp2.z) * (float)(s + 3)
                       + term_of(z2.w, w2.w, lp2.w) * (float)(s + 4);
        num += (double)fn;
        den += (double)((w2.x + w2.y) + (w2.z + w2.w));
    }
    {
        const int s = (int)(((base + 3 * BLOCK) << 2) & TCOL_MASK);
        const float fn = term_of(z3.x, w3.x, lp3.x) * (float)(s + 1)
                       + term_of(z3.y, w3.y, lp3.y) * (float)(s + 2)
                       + term_of(z3.z, w3.z, lp3.z) * (float)(s + 3)
                       + term_of(z3.w, w3.w, lp3.w) * (float)(s + 4);
        num += (double)fn;
        den += (double)((w3.x + w3.y) + (w3.z + w3.w));
    }

    block_reduce_and_finish(num, den, out, slots, count);
}

// Generic fallback (grid-stride, bounds-checked) — only if shape unexpected.
__global__ __launch_bounds__(BLOCK) void reinforce_generic(
    const float* __restrict__ log_probs,
    const float* __restrict__ logits,
    const float* __restrict__ weight,
    float* __restrict__ out,
    unsigned long long* __restrict__ slots,
    unsigned int* __restrict__ count,
    long long n4)
{
    const float4* __restrict__ lpv = (const float4*)log_probs;
    const float4* __restrict__ zv  = (const float4*)logits;
    const float4* __restrict__ wv  = (const float4*)weight;

    double num = 0.0, den = 0.0;
    const long long stride = (long long)gridDim.x * BLOCK;
    for (long long i = (long long)blockIdx.x * BLOCK + threadIdx.x; i < n4; i += stride) {
        const float4 lp = lpv[i];
        const float4 z  = zv[i];
        const float4 w  = wv[i];
        const int s = (int)((i << 2) & TCOL_MASK);
        const float fn = term_of(z.x, w.x, lp.x) * (float)(s + 1)
                       + term_of(z.y, w.y, lp.y) * (float)(s + 2)
                       + term_of(z.z, w.z, lp.z) * (float)(s + 3)
                       + term_of(z.w, w.w, lp.w) * (float)(s + 4);
        num += (double)fn;
        den += (double)((w.x + w.y) + (w.z + w.w));
    }
    block_reduce_and_finish(num, den, out, slots, count);
}

extern "C" void kernel_launch(void* const* d_in, const int* in_sizes, int n_in,
                              void* d_out, int out_size, void* d_ws, size_t ws_size,
                              hipStream_t stream) {
    const float* log_probs = (const float*)d_in[0];
    const float* logits    = (const float*)d_in[1];
    const float* weight    = (const float*)d_in[2];
    float* out = (float*)d_out;

    // slots at ws+0; counter parked 1 MiB in, away from the slot lines
    unsigned long long* slots = (unsigned long long*)d_ws;
    unsigned int* count = (unsigned int*)((char*)d_ws + (1 << 20));

    const long long N  = (long long)in_sizes[0];  // B*T = 8,388,608
    const long long n4 = N >> 2;                  // 2,097,152 float4s

    hipMemsetAsync(count, 0, sizeof(unsigned int), stream);

    if (n4 % (BLOCK * ITERS) == 0) {
        const int grid = (int)(n4 / (BLOCK * ITERS));   // 2048 for bench shape
        reinforce_fast<<<grid, BLOCK, 0, stream>>>(log_probs, logits, weight,
                                                   out, slots, count);
    } else {
        const int grid = 2048;
        reinforce_generic<<<grid, BLOCK, 0, stream>>>(log_probs, logits, weight,
                                                      out, slots, count, n4);
    }
}

// Round 7
// 115.981 us; speedup vs baseline: 1.8337x; 1.8337x over previous
//
#include <hip/hip_runtime.h>

#define EPS 1e-7f
#define BLOCK 256
#define ITERS 4
#define TCOL_MASK 16383   // T-1, T = 16384 (bench shape)

__device__ __forceinline__ float term_of(float z, float w, float lp) {
    const float r = __logf(1.f / (1.f + __expf(-z)) + EPS);
    return w * w * r * lp;
}

// Fast path: requires n4 % (BLOCK*ITERS) == 0. All 12 dwordx4 loads issued
// straight-line; split finalize kernel (single-kernel atomic finish regressed
// 2x in R2 and R6 — the epilogue forces a 32-VGPR serialized schedule).
__global__ __launch_bounds__(BLOCK, 4) void reinforce_partial_fast(
    const float* __restrict__ log_probs,
    const float* __restrict__ logits,
    const float* __restrict__ weight,
    double* __restrict__ parts)
{
    const float4* __restrict__ lpv = (const float4*)log_probs;
    const float4* __restrict__ zv  = (const float4*)logits;
    const float4* __restrict__ wv  = (const float4*)weight;

    const long long base = (long long)blockIdx.x * (BLOCK * ITERS) + threadIdx.x;

    const float4 z0  = zv[base];
    const float4 w0  = wv[base];
    const float4 lp0 = lpv[base];
    const float4 z1  = zv[base + BLOCK];
    const float4 w1  = wv[base + BLOCK];
    const float4 lp1 = lpv[base + BLOCK];
    const float4 z2  = zv[base + 2 * BLOCK];
    const float4 w2  = wv[base + 2 * BLOCK];
    const float4 lp2 = lpv[base + 2 * BLOCK];
    const float4 z3  = zv[base + 3 * BLOCK];
    const float4 w3  = wv[base + 3 * BLOCK];
    const float4 lp3 = lpv[base + 3 * BLOCK];

    double num = 0.0, den = 0.0;
    {
        const int s = (int)((base << 2) & TCOL_MASK);
        const float fn = term_of(z0.x, w0.x, lp0.x) * (float)(s + 1)
                       + term_of(z0.y, w0.y, lp0.y) * (float)(s + 2)
                       + term_of(z0.z, w0.z, lp0.z) * (float)(s + 3)
                       + term_of(z0.w, w0.w, lp0.w) * (float)(s + 4);
        num += (double)fn;
        den += (double)((w0.x + w0.y) + (w0.z + w0.w));
    }
    {
        const int s = (int)(((base + BLOCK) << 2) & TCOL_MASK);
        const float fn = term_of(z1.x, w1.x, lp1.x) * (float)(s + 1)
                       + term_of(z1.y, w1.y, lp1.y) * (float)(s + 2)
                       + term_of(z1.z, w1.z, lp1.z) * (float)(s + 3)
                       + term_of(z1.w, w1.w, lp1.w) * (float)(s + 4);
        num += (double)fn;
        den += (double)((w1.x + w1.y) + (w1.z + w1.w));
    }
    {
        const int s = (int)(((base + 2 * BLOCK) << 2) & TCOL_MASK);
        const float fn = term_of(z2.x, w2.x, lp2.x) * (float)(s + 1)
                       + term_of(z2.y, w2.y, lp2.y) * (float)(s + 2)
                       + term_of(z2.z, w2.z, lp2.z) * (float)(s + 3)
                       + term_of(z2.w, w2.w, lp2.w) * (float)(s + 4);
        num += (double)fn;
        den += (double)((w2.x + w2.y) + (w2.z + w2.w));
    }
    {
        const int s = (int)(((base + 3 * BLOCK) << 2) & TCOL_MASK);
        const float fn = term_of(z3.x, w3.x, lp3.x) * (float)(s + 1)
                       + term_of(z3.y, w3.y, lp3.y) * (float)(s + 2)
                       + term_of(z3.z, w3.z, lp3.z) * (float)(s + 3)
                       + term_of(z3.w, w3.w, lp3.w) * (float)(s + 4);
        num += (double)fn;
        den += (double)((w3.x + w3.y) + (w3.z + w3.w));
    }

#pragma unroll
    for (int off = 32; off > 0; off >>= 1) {
        num += __shfl_down(num, off, 64);
        den += __shfl_down(den, off, 64);
    }
    __shared__ double s_n[BLOCK / 64], s_d[BLOCK / 64];
    const int lane = threadIdx.x & 63;
    const int wid  = threadIdx.x >> 6;
    if (lane == 0) { s_n[wid] = num; s_d[wid] = den; }
    __syncthreads();
    if (threadIdx.x == 0) {
        parts[2 * blockIdx.x]     = (s_n[0] + s_n[1]) + (s_n[2] + s_n[3]);
        parts[2 * blockIdx.x + 1] = (s_d[0] + s_d[1]) + (s_d[2] + s_d[3]);
    }
}

// Generic fallback (grid-stride, bounds-checked) — only if shape unexpected.
__global__ __launch_bounds__(BLOCK) void reinforce_partial_generic(
    const float* __restrict__ log_probs,
    const float* __restrict__ logits,
    const float* __restrict__ weight,
    double* __restrict__ parts,
    long long n4)
{
    const float4* __restrict__ lpv = (const float4*)log_probs;
    const float4* __restrict__ zv  = (const float4*)logits;
    const float4* __restrict__ wv  = (const float4*)weight;

    double num = 0.0, den = 0.0;
    const long long stride = (long long)gridDim.x * BLOCK;
    for (long long i = (long long)blockIdx.x * BLOCK + threadIdx.x; i < n4; i += stride) {
        const float4 lp = lpv[i];
        const float4 z  = zv[i];
        const float4 w  = wv[i];
        const int s = (int)((i << 2) & TCOL_MASK);
        const float fn = term_of(z.x, w.x, lp.x) * (float)(s + 1)
                       + term_of(z.y, w.y, lp.y) * (float)(s + 2)
                       + term_of(z.z, w.z, lp.z) * (float)(s + 3)
                       + term_of(z.w, w.w, lp.w) * (float)(s + 4);
        num += (double)fn;
        den += (double)((w.x + w.y) + (w.z + w.w));
    }
#pragma unroll
    for (int off = 32; off > 0; off >>= 1) {
        num += __shfl_down(num, off, 64);
        den += __shfl_down(den, off, 64);
    }
    __shared__ double s_n[BLOCK / 64], s_d[BLOCK / 64];
    const int lane = threadIdx.x & 63;
    const int wid  = threadIdx.x >> 6;
    if (lane == 0) { s_n[wid] = num; s_d[wid] = den; }
    __syncthreads();
    if (threadIdx.x == 0) {
        parts[2 * blockIdx.x]     = (s_n[0] + s_n[1]) + (s_n[2] + s_n[3]);
        parts[2 * blockIdx.x + 1] = (s_d[0] + s_d[1]) + (s_d[2] + s_d[3]);
    }
}

__global__ __launch_bounds__(BLOCK) void reinforce_finalize(
    const double* __restrict__ parts, float* __restrict__ out, int nblocks)
{
    double n = 0.0, d = 0.0;
    for (int j = threadIdx.x; j < nblocks; j += BLOCK) {
        n += parts[2 * j];
        d += parts[2 * j + 1];
    }
#pragma unroll
    for (int off = 32; off > 0; off >>= 1) {
        n += __shfl_down(n, off, 64);
        d += __shfl_down(d, off, 64);
    }
    __shared__ double s_n[BLOCK / 64], s_d[BLOCK / 64];
    const int lane = threadIdx.x & 63;
    const int wid  = threadIdx.x >> 6;
    if (lane == 0) { s_n[wid] = n; s_d[wid] = d; }
    __syncthreads();
    if (threadIdx.x == 0) {
        out[0] = (float)(((s_n[0] + s_n[1]) + (s_n[2] + s_n[3])) /
                         ((s_d[0] + s_d[1]) + (s_d[2] + s_d[3])));
    }
}

extern "C" void kernel_launch(void* const* d_in, const int* in_sizes, int n_in,
                              void* d_out, int out_size, void* d_ws, size_t ws_size,
                              hipStream_t stream) {
    const float* log_probs = (const float*)d_in[0];
    const float* logits    = (const float*)d_in[1];
    const float* weight    = (const float*)d_in[2];
    float* out = (float*)d_out;
    double* parts = (double*)d_ws;

    const long long N  = (long long)in_sizes[0];  // B*T = 8,388,608
    const long long n4 = N >> 2;                  // 2,097,152 float4s

    if (n4 % (BLOCK * ITERS) == 0) {
        const int grid = (int)(n4 / (BLOCK * ITERS));   // 2048 for bench shape
        reinforce_partial_fast<<<grid, BLOCK, 0, stream>>>(log_probs, logits, weight, parts);
        reinforce_finalize<<<1, BLOCK, 0, stream>>>(parts, out, grid);
    } else {
        const int grid = 2048;
        reinforce_partial_generic<<<grid, BLOCK, 0, stream>>>(log_probs, logits, weight, parts, n4);
        reinforce_finalize<<<1, BLOCK, 0, stream>>>(parts, out, grid);
    }
}